// Round 4
// baseline (309.283 us; speedup 1.0000x reference)
//
#include <hip/hip_runtime.h>
#include <hip/hip_bf16.h>
#include <math.h>

// Fully-fused hash-encode + 4-layer MLP, v4.
// vs v3: 64-row blocks -> 74 KB LDS -> 2 blocks/CU, 4 waves/SIMD (2x occupancy);
// wave tile 64x64 (acc[4][4]); L0 staging pitch 80 B (bank-uniform);
// af loaded per-mi (register relief). Rolled K-loops, swapped-operand MFMA.

#define T_SIZE 524288   // 2^19
#define T_MASK (T_SIZE - 1)

typedef _Float16 f16;
typedef _Float16 f16x8 __attribute__((ext_vector_type(8)));
typedef _Float16 f16x4 __attribute__((ext_vector_type(4)));
typedef float f32x4 __attribute__((ext_vector_type(4)));

struct Scales { float s[16]; };

// ---------------- weight -> fragment-linear f16 ----------------
// Wf[frag][lane][8]: frag = nblk*(K/32)+ks; (lane,j) = W[ks*32+(lane>>4)*8+j][nblk*16+(lane&15)]
__global__ void wfrag(const float* __restrict__ W, f16* __restrict__ Wf, int K, int N) {
  int tid = blockIdx.x * 256 + threadIdx.x;
  int lane = tid & 63, frag = tid >> 6;
  int KS = K >> 5;
  int nblk = frag / KS, ks = frag - nblk * KS;
  if (nblk * 16 >= N) return;
  int n = nblk * 16 + (lane & 15);
  int kb = ks * 32 + (lane >> 4) * 8;
  f16x8 v;
#pragma unroll
  for (int j = 0; j < 8; ++j) v[j] = (f16)W[(size_t)(kb + j) * N + n];
  *(f16x8*)(Wf + (size_t)frag * 512 + lane * 8) = v;
}

__device__ __forceinline__ float silu_f(float v) {
  return v * __builtin_amdgcn_rcpf(1.f + __expf(-v));
}

// ---------------- fused MLP ----------------
// block = 64 rows, 8 waves; wave w owns cols [64w, 64w+64) (L3B: 32 cols).
__global__ __launch_bounds__(512, 4) void fused_mlp(
    const float* __restrict__ x, const float* __restrict__ t,
    const float* __restrict__ cond, const float* __restrict__ tables,
    const f16* __restrict__ Wf0, const f16* __restrict__ Wf1,
    const f16* __restrict__ Wf2, const f16* __restrict__ Wf3,
    const float* __restrict__ b0, const float* __restrict__ b1,
    const float* __restrict__ b2, const float* __restrict__ b3,
    float* __restrict__ out, Scales scl) {
  __shared__ f16 act[64 * 512];     // 64 KB, swizzled: elem = r*512 + (c ^ ((r&7)<<3))
  __shared__ f16 stg[2 * 64 * 40];  // 10 KB dbuf, pitch 40 f16 = 80 B (bank-uniform)

  const int tid = threadIdx.x;
  const int wave = tid >> 6, lane = tid & 63;
  const int l16 = lane & 15, lhi = lane >> 4;
  const int rowBase = blockIdx.x * 64;
  const int sr = tid >> 3, sc = tid & 7;          // staging: 8 threads/row, 4 f16 each

  // ---- hash-grid encode: thread (sr,sc) computes levels sc and sc+8 of row sr ----
  f16x4 er_a, er_b;   // staged at ks=24 (levels 0..7) / ks=25 (levels 8..15)
  {
    int row = rowBase + sr;
    float c0 = cond[2 * row], c1 = cond[2 * row + 1], c2 = t[row];
#pragma unroll
    for (int h = 0; h < 2; ++h) {
      int l = sc + h * 8;
      float s = scl.s[l];
      float xf0 = c0 * s, xf1 = c1 * s, xf2 = c2 * s;
      float xl0 = floorf(xf0), xl1 = floorf(xf1), xl2 = floorf(xf2);
      float w0 = xf0 - xl0, w1 = xf1 - xl1, w2 = xf2 - xl2;
      unsigned xi0 = (unsigned)xl0, xi1 = (unsigned)xl1, xi2 = (unsigned)xl2;
      const float4* tl = (const float4*)tables + (size_t)l * T_SIZE;
      float a0 = 0.f, a1 = 0.f, a2 = 0.f, a3 = 0.f;
#pragma unroll
      for (int c = 0; c < 8; ++c) {
        unsigned ax = (c >> 2) & 1u, ay = (c >> 1) & 1u, az = c & 1u;
        unsigned hh = (xi0 + ax) ^ ((xi1 + ay) * 2654435761u) ^ ((xi2 + az) * 805459861u);
        float4 f = tl[hh & T_MASK];
        float wcw = (ax ? w0 : 1.f - w0) * (ay ? w1 : 1.f - w1) * (az ? w2 : 1.f - w2);
        a0 += wcw * f.x; a1 += wcw * f.y; a2 += wcw * f.z; a3 += wcw * f.w;
      }
      f16x4 er = { (f16)a0, (f16)a1, (f16)a2, (f16)a3 };
      if (h == 0) er_a = er; else er_b = er;
    }
  }

  f32x4 acc[4][4];
  f16x8 bfA[4], bfB[4];

  // ================= Layer 0: K = 832 =================
#pragma unroll
  for (int mi = 0; mi < 4; ++mi)
#pragma unroll
    for (int ni = 0; ni < 4; ++ni) acc[mi][ni] = (f32x4){0.f, 0.f, 0.f, 0.f};

  {  // stage ks=0
    float4 a = *(const float4*)(x + (size_t)(rowBase + sr) * 768 + sc * 4);
    f16x4 v = { (f16)a.x, (f16)a.y, (f16)a.z, (f16)a.w };
    *(f16x4*)(stg + sr * 40 + sc * 4) = v;
  }
#pragma unroll
  for (int ni = 0; ni < 4; ++ni)
    bfA[ni] = *(const f16x8*)(Wf0 + ((size_t)(wave * 4 + ni) * 26) * 512 + lane * 8);
  __syncthreads();

#pragma unroll 1
  for (int ks = 0; ks < 26; ++ks) {
    const int nxt = ks + 1;
    f16x4 nv;
    if (nxt < 24) {
      float4 a = *(const float4*)(x + (size_t)(rowBase + sr) * 768 + nxt * 32 + sc * 4);
      nv = (f16x4){ (f16)a.x, (f16)a.y, (f16)a.z, (f16)a.w };
    } else {
      nv = (nxt == 24) ? er_a : er_b;
    }
    if (nxt < 26) {
#pragma unroll
      for (int ni = 0; ni < 4; ++ni)
        bfB[ni] = *(const f16x8*)(Wf0 + ((size_t)(wave * 4 + ni) * 26 + nxt) * 512 + lane * 8);
    }
    const f16* rb = stg + (ks & 1) * 2560;
    __builtin_amdgcn_s_setprio(1);
#pragma unroll
    for (int mi = 0; mi < 4; ++mi) {
      f16x8 af = *(const f16x8*)(rb + (mi * 16 + l16) * 40 + lhi * 8);
#pragma unroll
      for (int ni = 0; ni < 4; ++ni)
        acc[mi][ni] = __builtin_amdgcn_mfma_f32_16x16x32_f16(bfA[ni], af, acc[mi][ni], 0, 0, 0);
    }
    __builtin_amdgcn_s_setprio(0);
    if (nxt < 26) {
      *(f16x4*)(stg + (nxt & 1) * 2560 + sr * 40 + sc * 4) = nv;
#pragma unroll
      for (int ni = 0; ni < 4; ++ni) bfA[ni] = bfB[ni];
    }
    __syncthreads();
  }

  // epilogue -> act (bias + silu). D-frag (swapped): act-row = mi*16+l16,
  // cols = wave*64 + ni*16 + lhi*4 .. +3 (consecutive -> f16x4 store)
  auto epi_act = [&](const float* __restrict__ bias) {
    __syncthreads();
#pragma unroll
    for (int mi = 0; mi < 4; ++mi) {
      const int row = mi * 16 + l16;
#pragma unroll
      for (int ni = 0; ni < 4; ++ni) {
        const int col = wave * 64 + ni * 16 + lhi * 4;
        float4 bv = *(const float4*)(bias + col);
        f16x4 o;
        o[0] = (f16)silu_f(acc[mi][ni][0] + bv.x);
        o[1] = (f16)silu_f(acc[mi][ni][1] + bv.y);
        o[2] = (f16)silu_f(acc[mi][ni][2] + bv.z);
        o[3] = (f16)silu_f(acc[mi][ni][3] + bv.w);
        *(f16x4*)(act + row * 512 + (col ^ ((row & 7) << 3))) = o;
      }
    }
    __syncthreads();
  };
  epi_act(b0);

  // ================= K=512 loop (layers 1,2,3A) =================
  auto kloop4 = [&](const f16* __restrict__ Wf) {
#pragma unroll
    for (int mi = 0; mi < 4; ++mi)
#pragma unroll
      for (int ni = 0; ni < 4; ++ni) acc[mi][ni] = (f32x4){0.f, 0.f, 0.f, 0.f};
#pragma unroll
    for (int ni = 0; ni < 4; ++ni)
      bfA[ni] = *(const f16x8*)(Wf + ((size_t)(wave * 4 + ni) * 16) * 512 + lane * 8);
#pragma unroll 1
    for (int ks = 0; ks < 16; ++ks) {
      if (ks < 15) {
#pragma unroll
        for (int ni = 0; ni < 4; ++ni)
          bfB[ni] = *(const f16x8*)(Wf + ((size_t)(wave * 4 + ni) * 16 + ks + 1) * 512 + lane * 8);
      }
      __builtin_amdgcn_s_setprio(1);
#pragma unroll
      for (int mi = 0; mi < 4; ++mi) {
        int r = mi * 16 + l16;
        f16x8 af = *(const f16x8*)(act + r * 512 + ((ks * 32 + lhi * 8) ^ ((r & 7) << 3)));
#pragma unroll
        for (int ni = 0; ni < 4; ++ni)
          acc[mi][ni] = __builtin_amdgcn_mfma_f32_16x16x32_f16(bfA[ni], af, acc[mi][ni], 0, 0, 0);
      }
      __builtin_amdgcn_s_setprio(0);
      if (ks < 15) {
#pragma unroll
        for (int ni = 0; ni < 4; ++ni) bfA[ni] = bfB[ni];
      }
    }
  };

  kloop4(Wf1); epi_act(b1);
  kloop4(Wf2); epi_act(b2);

  // Layer 3 pass A: cols 0..511
  kloop4(Wf3);
#pragma unroll
  for (int mi = 0; mi < 4; ++mi) {
    const size_t row = (size_t)(rowBase + mi * 16 + l16);
#pragma unroll
    for (int ni = 0; ni < 4; ++ni) {
      const int col = wave * 64 + ni * 16 + lhi * 4;
      float4 bv = *(const float4*)(b3 + col);
      float4 o = { acc[mi][ni][0] + bv.x, acc[mi][ni][1] + bv.y,
                   acc[mi][ni][2] + bv.z, acc[mi][ni][3] + bv.w };
      *(float4*)(out + row * 768 + col) = o;
    }
  }

  // Layer 3 pass B: cols 512..767 (wave w -> cols 512+32w .. +31, ni 0..1)
#pragma unroll
  for (int mi = 0; mi < 4; ++mi)
#pragma unroll
    for (int ni = 0; ni < 2; ++ni) acc[mi][ni] = (f32x4){0.f, 0.f, 0.f, 0.f};
#pragma unroll
  for (int ni = 0; ni < 2; ++ni)
    bfA[ni] = *(const f16x8*)(Wf3 + ((size_t)(32 + wave * 2 + ni) * 16) * 512 + lane * 8);
#pragma unroll 1
  for (int ks = 0; ks < 16; ++ks) {
    if (ks < 15) {
#pragma unroll
      for (int ni = 0; ni < 2; ++ni)
        bfB[ni] = *(const f16x8*)(Wf3 + ((size_t)(32 + wave * 2 + ni) * 16 + ks + 1) * 512 + lane * 8);
    }
    __builtin_amdgcn_s_setprio(1);
#pragma unroll
    for (int mi = 0; mi < 4; ++mi) {
      int r = mi * 16 + l16;
      f16x8 af = *(const f16x8*)(act + r * 512 + ((ks * 32 + lhi * 8) ^ ((r & 7) << 3)));
#pragma unroll
      for (int ni = 0; ni < 2; ++ni)
        acc[mi][ni] = __builtin_amdgcn_mfma_f32_16x16x32_f16(bfA[ni], af, acc[mi][ni], 0, 0, 0);
    }
    __builtin_amdgcn_s_setprio(0);
    if (ks < 15) {
#pragma unroll
      for (int ni = 0; ni < 2; ++ni) bfA[ni] = bfB[ni];
    }
  }
#pragma unroll
  for (int mi = 0; mi < 4; ++mi) {
    const size_t row = (size_t)(rowBase + mi * 16 + l16);
#pragma unroll
    for (int ni = 0; ni < 2; ++ni) {
      const int col = 512 + wave * 32 + ni * 16 + lhi * 4;
      float4 bv = *(const float4*)(b3 + col);
      float4 o = { acc[mi][ni][0] + bv.x, acc[mi][ni][1] + bv.y,
                   acc[mi][ni][2] + bv.z, acc[mi][ni][3] + bv.w };
      *(float4*)(out + row * 768 + col) = o;
    }
  }
}

// ---------------- launch ----------------
extern "C" void kernel_launch(void* const* d_in, const int* in_sizes, int n_in,
                              void* d_out, int out_size, void* d_ws, size_t ws_size,
                              hipStream_t stream) {
  const float* t    = (const float*)d_in[0];
  const float* x    = (const float*)d_in[1];
  const float* cond = (const float*)d_in[2];
  const float* tab  = (const float*)d_in[3];
  const float* W0   = (const float*)d_in[4];
  const float* b0   = (const float*)d_in[5];
  const float* W1   = (const float*)d_in[6];
  const float* b1   = (const float*)d_in[7];
  const float* W2   = (const float*)d_in[8];
  const float* b2   = (const float*)d_in[9];
  const float* W3   = (const float*)d_in[10];
  const float* b3   = (const float*)d_in[11];
  float* out = (float*)d_out;
  (void)in_sizes; (void)n_in; (void)out_size; (void)ws_size;

  char* ws = (char*)d_ws;
  f16* Wf0 = (f16*)(ws + 0);            // 832*512*2 = 851968
  f16* Wf1 = (f16*)(ws + 851968);       // 524288
  f16* Wf2 = (f16*)(ws + 1376256);      // 524288
  f16* Wf3 = (f16*)(ws + 1900544);      // 786432

  wfrag<<<dim3(208), 256, 0, stream>>>(W0, Wf0, 832, 512);
  wfrag<<<dim3(128), 256, 0, stream>>>(W1, Wf1, 512, 512);
  wfrag<<<dim3(128), 256, 0, stream>>>(W2, Wf2, 512, 512);
  wfrag<<<dim3(192), 256, 0, stream>>>(W3, Wf3, 512, 768);

  Scales sc;
  {
    double growth = exp((log(512.0) - log(16.0)) / 15.0);
    for (int l = 0; l < 16; ++l) sc.s[l] = (float)floor(16.0 * pow(growth, (double)l));
  }

  fused_mlp<<<dim3(1024), 512, 0, stream>>>(x, t, cond, tab, Wf0, Wf1, Wf2, Wf3,
                                            b0, b1, b2, b3, out, sc);
}

// Round 5
// 301.521 us; speedup vs baseline: 1.0257x; 1.0257x over previous
//
#include <hip/hip_runtime.h>
#include <hip/hip_bf16.h>
#include <math.h>

// Fully-fused hash-encode + 4-layer MLP, v5.
// vs v4: K-loops hand-unrolled 2x with ping-pong weight register sets and
// prefetch distance 2 -> counted vmcnt (no per-step vmcnt(0) drain), no
// bfA=bfB copies; setprio removed. Structure otherwise identical to v4.

#define T_SIZE 524288   // 2^19
#define T_MASK (T_SIZE - 1)

typedef _Float16 f16;
typedef _Float16 f16x8 __attribute__((ext_vector_type(8)));
typedef _Float16 f16x4 __attribute__((ext_vector_type(4)));
typedef float f32x4 __attribute__((ext_vector_type(4)));

struct Scales { float s[16]; };

// ---------------- weight -> fragment-linear f16 ----------------
// Wf[frag][lane][8]: frag = nblk*(K/32)+ks; (lane,j) = W[ks*32+(lane>>4)*8+j][nblk*16+(lane&15)]
__global__ void wfrag(const float* __restrict__ W, f16* __restrict__ Wf, int K, int N) {
  int tid = blockIdx.x * 256 + threadIdx.x;
  int lane = tid & 63, frag = tid >> 6;
  int KS = K >> 5;
  int nblk = frag / KS, ks = frag - nblk * KS;
  if (nblk * 16 >= N) return;
  int n = nblk * 16 + (lane & 15);
  int kb = ks * 32 + (lane >> 4) * 8;
  f16x8 v;
#pragma unroll
  for (int j = 0; j < 8; ++j) v[j] = (f16)W[(size_t)(kb + j) * N + n];
  *(f16x8*)(Wf + (size_t)frag * 512 + lane * 8) = v;
}

__device__ __forceinline__ float silu_f(float v) {
  return v * __builtin_amdgcn_rcpf(1.f + __expf(-v));
}

// K=512 main loop, deep-prefetch ping-pong (distance 2, counted vmcnt).
// frag (ni,ks) of wave's cols at Wf[(fragRow0+ni)*KSTEPS + ks].
template<int NF, int KSTEPS>
__device__ __forceinline__ void kloop_dp(
    const f16* __restrict__ actS, const f16* __restrict__ Wf, int fragRow0,
    int l16, int lhi, int lane, f32x4 (&acc)[4][4]) {
#pragma unroll
  for (int mi = 0; mi < 4; ++mi)
#pragma unroll
    for (int ni = 0; ni < NF; ++ni) acc[mi][ni] = (f32x4){0.f, 0.f, 0.f, 0.f};

  f16x8 bfU[NF], bfV[NF];
  const f16* wbase = Wf + ((size_t)fragRow0 * KSTEPS) * 512 + lane * 8;
#pragma unroll
  for (int ni = 0; ni < NF; ++ni)
    bfU[ni] = *(const f16x8*)(wbase + (size_t)(ni * KSTEPS + 0) * 512);
#pragma unroll
  for (int ni = 0; ni < NF; ++ni)
    bfV[ni] = *(const f16x8*)(wbase + (size_t)(ni * KSTEPS + 1) * 512);

#pragma unroll 1
  for (int ks = 0; ks < KSTEPS; ks += 2) {
    f16x8 af[4];
    // ---- even sub-step: consume U ----
#pragma unroll
    for (int mi = 0; mi < 4; ++mi) {
      int r = mi * 16 + l16;
      af[mi] = *(const f16x8*)(actS + r * 512 + ((ks * 32 + lhi * 8) ^ ((r & 7) << 3)));
    }
#pragma unroll
    for (int mi = 0; mi < 4; ++mi)
#pragma unroll
      for (int ni = 0; ni < NF; ++ni)
        acc[mi][ni] = __builtin_amdgcn_mfma_f32_16x16x32_f16(bfU[ni], af[mi], acc[mi][ni], 0, 0, 0);
    if (ks + 2 < KSTEPS) {            // prefetch U for ks+2 (after reads: WAR-safe)
#pragma unroll
      for (int ni = 0; ni < NF; ++ni)
        bfU[ni] = *(const f16x8*)(wbase + (size_t)(ni * KSTEPS + ks + 2) * 512);
    }
    // ---- odd sub-step: consume V ----
#pragma unroll
    for (int mi = 0; mi < 4; ++mi) {
      int r = mi * 16 + l16;
      af[mi] = *(const f16x8*)(actS + r * 512 + (((ks + 1) * 32 + lhi * 8) ^ ((r & 7) << 3)));
    }
#pragma unroll
    for (int mi = 0; mi < 4; ++mi)
#pragma unroll
      for (int ni = 0; ni < NF; ++ni)
        acc[mi][ni] = __builtin_amdgcn_mfma_f32_16x16x32_f16(bfV[ni], af[mi], acc[mi][ni], 0, 0, 0);
    if (ks + 3 < KSTEPS) {            // prefetch V for ks+3
#pragma unroll
      for (int ni = 0; ni < NF; ++ni)
        bfV[ni] = *(const f16x8*)(wbase + (size_t)(ni * KSTEPS + ks + 3) * 512);
    }
  }
}

// ---------------- fused MLP ----------------
// block = 64 rows, 8 waves; wave w owns cols [64w, 64w+64).
__global__ __launch_bounds__(512, 4) void fused_mlp(
    const float* __restrict__ x, const float* __restrict__ t,
    const float* __restrict__ cond, const float* __restrict__ tables,
    const f16* __restrict__ Wf0, const f16* __restrict__ Wf1,
    const f16* __restrict__ Wf2, const f16* __restrict__ Wf3,
    const float* __restrict__ b0, const float* __restrict__ b1,
    const float* __restrict__ b2, const float* __restrict__ b3,
    float* __restrict__ out, Scales scl) {
  __shared__ f16 act[64 * 512];     // 64 KB, swizzled: elem = r*512 + (c ^ ((r&7)<<3))
  __shared__ f16 stg[2 * 64 * 40];  // 10 KB dbuf, pitch 40 f16 = 80 B (bank-uniform)

  const int tid = threadIdx.x;
  const int wave = tid >> 6, lane = tid & 63;
  const int l16 = lane & 15, lhi = lane >> 4;
  const int rowBase = blockIdx.x * 64;
  const int sr = tid >> 3, sc = tid & 7;          // staging: 8 threads/row, 4 f16 each

  // ---- hash-grid encode: thread (sr,sc) computes levels sc and sc+8 of row sr ----
  f16x4 er_a, er_b;   // staged at ks=24 (levels 0..7) / ks=25 (levels 8..15)
  {
    int row = rowBase + sr;
    float c0 = cond[2 * row], c1 = cond[2 * row + 1], c2 = t[row];
#pragma unroll
    for (int h = 0; h < 2; ++h) {
      int l = sc + h * 8;
      float s = scl.s[l];
      float xf0 = c0 * s, xf1 = c1 * s, xf2 = c2 * s;
      float xl0 = floorf(xf0), xl1 = floorf(xf1), xl2 = floorf(xf2);
      float w0 = xf0 - xl0, w1 = xf1 - xl1, w2 = xf2 - xl2;
      unsigned xi0 = (unsigned)xl0, xi1 = (unsigned)xl1, xi2 = (unsigned)xl2;
      const float4* tl = (const float4*)tables + (size_t)l * T_SIZE;
      float a0 = 0.f, a1 = 0.f, a2 = 0.f, a3 = 0.f;
#pragma unroll
      for (int c = 0; c < 8; ++c) {
        unsigned ax = (c >> 2) & 1u, ay = (c >> 1) & 1u, az = c & 1u;
        unsigned hh = (xi0 + ax) ^ ((xi1 + ay) * 2654435761u) ^ ((xi2 + az) * 805459861u);
        float4 f = tl[hh & T_MASK];
        float wcw = (ax ? w0 : 1.f - w0) * (ay ? w1 : 1.f - w1) * (az ? w2 : 1.f - w2);
        a0 += wcw * f.x; a1 += wcw * f.y; a2 += wcw * f.z; a3 += wcw * f.w;
      }
      f16x4 er = { (f16)a0, (f16)a1, (f16)a2, (f16)a3 };
      if (h == 0) er_a = er; else er_b = er;
    }
  }

  f32x4 acc[4][4];

  // ================= Layer 0: K = 832 (barrier-staged, 1-deep) =================
#pragma unroll
  for (int mi = 0; mi < 4; ++mi)
#pragma unroll
    for (int ni = 0; ni < 4; ++ni) acc[mi][ni] = (f32x4){0.f, 0.f, 0.f, 0.f};

  {  // stage ks=0
    float4 a = *(const float4*)(x + (size_t)(rowBase + sr) * 768 + sc * 4);
    f16x4 v = { (f16)a.x, (f16)a.y, (f16)a.z, (f16)a.w };
    *(f16x4*)(stg + sr * 40 + sc * 4) = v;
  }
  f16x8 bfA[4], bfB[4];
#pragma unroll
  for (int ni = 0; ni < 4; ++ni)
    bfA[ni] = *(const f16x8*)(Wf0 + ((size_t)(wave * 4 + ni) * 26) * 512 + lane * 8);
  __syncthreads();

#pragma unroll 1
  for (int ks = 0; ks < 26; ++ks) {
    const int nxt = ks + 1;
    f16x4 nv;
    if (nxt < 24) {
      float4 a = *(const float4*)(x + (size_t)(rowBase + sr) * 768 + nxt * 32 + sc * 4);
      nv = (f16x4){ (f16)a.x, (f16)a.y, (f16)a.z, (f16)a.w };
    } else {
      nv = (nxt == 24) ? er_a : er_b;
    }
    if (nxt < 26) {
#pragma unroll
      for (int ni = 0; ni < 4; ++ni)
        bfB[ni] = *(const f16x8*)(Wf0 + ((size_t)(wave * 4 + ni) * 26 + nxt) * 512 + lane * 8);
    }
    const f16* rb = stg + (ks & 1) * 2560;
#pragma unroll
    for (int mi = 0; mi < 4; ++mi) {
      f16x8 af = *(const f16x8*)(rb + (mi * 16 + l16) * 40 + lhi * 8);
#pragma unroll
      for (int ni = 0; ni < 4; ++ni)
        acc[mi][ni] = __builtin_amdgcn_mfma_f32_16x16x32_f16(bfA[ni], af, acc[mi][ni], 0, 0, 0);
    }
    if (nxt < 26) {
      *(f16x4*)(stg + (nxt & 1) * 2560 + sr * 40 + sc * 4) = nv;
#pragma unroll
      for (int ni = 0; ni < 4; ++ni) bfA[ni] = bfB[ni];
    }
    __syncthreads();
  }

  // epilogue -> act (bias + silu). D-frag (swapped): act-row = mi*16+l16,
  // cols = wave*64 + ni*16 + lhi*4 .. +3 (consecutive -> f16x4 store)
  auto epi_act = [&](const float* __restrict__ bias) {
    __syncthreads();
#pragma unroll
    for (int mi = 0; mi < 4; ++mi) {
      const int row = mi * 16 + l16;
#pragma unroll
      for (int ni = 0; ni < 4; ++ni) {
        const int col = wave * 64 + ni * 16 + lhi * 4;
        float4 bv = *(const float4*)(bias + col);
        f16x4 o;
        o[0] = (f16)silu_f(acc[mi][ni][0] + bv.x);
        o[1] = (f16)silu_f(acc[mi][ni][1] + bv.y);
        o[2] = (f16)silu_f(acc[mi][ni][2] + bv.z);
        o[3] = (f16)silu_f(acc[mi][ni][3] + bv.w);
        *(f16x4*)(act + row * 512 + (col ^ ((row & 7) << 3))) = o;
      }
    }
    __syncthreads();
  };
  epi_act(b0);

  // ================= Layers 1,2: K=512 =================
  kloop_dp<4, 16>(act, Wf1, wave * 4, l16, lhi, lane, acc); epi_act(b1);
  kloop_dp<4, 16>(act, Wf2, wave * 4, l16, lhi, lane, acc); epi_act(b2);

  // ================= Layer 3 pass A: cols 0..511 =================
  kloop_dp<4, 16>(act, Wf3, wave * 4, l16, lhi, lane, acc);
#pragma unroll
  for (int mi = 0; mi < 4; ++mi) {
    const size_t row = (size_t)(rowBase + mi * 16 + l16);
#pragma unroll
    for (int ni = 0; ni < 4; ++ni) {
      const int col = wave * 64 + ni * 16 + lhi * 4;
      float4 bv = *(const float4*)(b3 + col);
      float4 o = { acc[mi][ni][0] + bv.x, acc[mi][ni][1] + bv.y,
                   acc[mi][ni][2] + bv.z, acc[mi][ni][3] + bv.w };
      *(float4*)(out + row * 768 + col) = o;
    }
  }

  // ================= Layer 3 pass B: cols 512..767 =================
  kloop_dp<2, 16>(act, Wf3, 32 + wave * 2, l16, lhi, lane, acc);
#pragma unroll
  for (int mi = 0; mi < 4; ++mi) {
    const size_t row = (size_t)(rowBase + mi * 16 + l16);
#pragma unroll
    for (int ni = 0; ni < 2; ++ni) {
      const int col = 512 + wave * 32 + ni * 16 + lhi * 4;
      float4 bv = *(const float4*)(b3 + col);
      float4 o = { acc[mi][ni][0] + bv.x, acc[mi][ni][1] + bv.y,
                   acc[mi][ni][2] + bv.z, acc[mi][ni][3] + bv.w };
      *(float4*)(out + row * 768 + col) = o;
    }
  }
}

// ---------------- launch ----------------
extern "C" void kernel_launch(void* const* d_in, const int* in_sizes, int n_in,
                              void* d_out, int out_size, void* d_ws, size_t ws_size,
                              hipStream_t stream) {
  const float* t    = (const float*)d_in[0];
  const float* x    = (const float*)d_in[1];
  const float* cond = (const float*)d_in[2];
  const float* tab  = (const float*)d_in[3];
  const float* W0   = (const float*)d_in[4];
  const float* b0   = (const float*)d_in[5];
  const float* W1   = (const float*)d_in[6];
  const float* b1   = (const float*)d_in[7];
  const float* W2   = (const float*)d_in[8];
  const float* b2   = (const float*)d_in[9];
  const float* W3   = (const float*)d_in[10];
  const float* b3   = (const float*)d_in[11];
  float* out = (float*)d_out;
  (void)in_sizes; (void)n_in; (void)out_size; (void)ws_size;

  char* ws = (char*)d_ws;
  f16* Wf0 = (f16*)(ws + 0);            // 832*512*2 = 851968
  f16* Wf1 = (f16*)(ws + 851968);       // 524288
  f16* Wf2 = (f16*)(ws + 1376256);      // 524288
  f16* Wf3 = (f16*)(ws + 1900544);      // 786432

  wfrag<<<dim3(208), 256, 0, stream>>>(W0, Wf0, 832, 512);
  wfrag<<<dim3(128), 256, 0, stream>>>(W1, Wf1, 512, 512);
  wfrag<<<dim3(128), 256, 0, stream>>>(W2, Wf2, 512, 512);
  wfrag<<<dim3(192), 256, 0, stream>>>(W3, Wf3, 512, 768);

  Scales sc;
  {
    double growth = exp((log(512.0) - log(16.0)) / 15.0);
    for (int l = 0; l < 16; ++l) sc.s[l] = (float)floor(16.0 * pow(growth, (double)l));
  }

  fused_mlp<<<dim3(1024), 512, 0, stream>>>(x, t, cond, tab, Wf0, Wf1, Wf2, Wf3,
                                            b0, b1, b2, b3, out, sc);
}